// Round 7
// baseline (540.771 us; speedup 1.0000x reference)
//
#include <hip/hip_runtime.h>

#define BB 16
#define CC 32
#define HH 256
#define WW 256

#define TWV 30    // valid conv2 output cols per block (conv1 computed on 32)
#define TH 8      // rows per iteration (8 waves x 1 row)
#define NT 4      // conv2 iterations per block (conv1 does NT+1)
#define CIP 36    // padded ci stride: 72 B -> 2-way LDS banks (free), 8B-aligned

typedef short bf16x8 __attribute__((ext_vector_type(8)));
typedef float f32x16 __attribute__((ext_vector_type(16)));

struct alignas(8)  U2 { unsigned x, y; };
struct alignas(16) U4 { U2 lo, hi; };

__device__ __forceinline__ unsigned short f2bf(float f) {
    unsigned u = __float_as_uint(f);
    u += 0x7fffu + ((u >> 16) & 1u);   // RNE
    return (unsigned short)(u >> 16);
}

// HW packed f32->bf16 (RNE).
__device__ __forceinline__ unsigned cvtpk(float lo, float hi) {
    unsigned r;
    asm("v_cvt_pk_bf16_f32 %0, %1, %2" : "=v"(r) : "v"(lo), "v"(hi));
    return r;
}

// Pre-swizzle weights into per-lane MFMA A-fragment order, bf16:
// wq[layer][st(18)][half(2)][n=co(32)][j(8)], value = w[co][ci][pos]
// with pos = st>>1 (kh*3+kw), ci = (st&1)*16 + half*8 + j.
__global__ void wprep(const float* __restrict__ w1, const float* __restrict__ w2,
                      unsigned short* __restrict__ wq) {
    int idx = blockIdx.x * 256 + threadIdx.x;   // 0..9215
    if (idx >= 18 * 2 * 32 * 8) return;
    int j    = idx & 7;
    int n    = (idx >> 3) & 31;
    int half = (idx >> 8) & 1;
    int st   = idx >> 9;
    int s = st & 1, pos = st >> 1;
    int ci = s * 16 + half * 8 + j;
    int src = (n * CC + ci) * 9 + pos;
    wq[idx]        = f2bf(w1[src]);
    wq[9216 + idx] = f2bf(w2[src]);
}

// Fully fused: conv1 (bias1*gate, relu) -> LDS ring -> conv2 (bias2*gate, relu) + resid.
// 8 waves, 1 output row per wave; 2 blocks/CU x 8 waves = 16 waves/CU.
// Weight fragments are NOT kept resident (that would spill at the 128-VGPR cap):
// each MFMA body reloads its 18 fragments from the L2-hot 36 KB table.
__global__ __launch_bounds__(512, 4)
void conv_fused(const float* __restrict__ x,             // fp32 NCHW (input + residual)
                const unsigned short* __restrict__ wq,   // layer1 table; layer2 at +9216 ushorts
                const float* __restrict__ b1v,
                const float* __restrict__ b2v,
                const float* __restrict__ gate,
                float* __restrict__ out)
{
    __shared__ unsigned short xs[TH + 2][34][CIP];      // 10*34*36*2 = 24480 B
    __shared__ unsigned short hs[2][TH][34][CIP];       // 2*8*34*36*2 = 39168 B (cols 32,33 pad)
    __shared__ float gs[CC], bs1[CC], bs2[CC];

    const int t     = threadIdx.x;
    const int b     = blockIdx.z;
    const int x0    = blockIdx.x * TWV;
    const int ybase = blockIdx.y * (TH * NT);

    if (t < CC) {
        float gv = gate[b * CC + t];
        gs[t]  = gv > 0.f ? gv : 0.f;
        bs1[t] = b1v[t];
        bs2[t] = b2v[t];
    }

    const int lane = t & 63;
    const int wv   = t >> 6;       // wave 0..7 = output row within chunk
    const int col  = lane & 31;    // MFMA n (pixel/col) and A m (co) lane index
    const int half = lane >> 5;

    // Per-lane fragment slot in the weight tables (U4 units); st adds 64/step.
    const int wslot = half * 32 + col;
    const U4* wq1 = (const U4*)wq + wslot;
    const U4* wq2 = (const U4*)(wq + 9216) + wslot;

    // Staging: one pixel per thread (340 = 10x34 pixels; threads 340..511 idle).
    const int yA = t / 34, xA = t - yA * 34;
    const bool hasA = t < 340;
    const float* xb = x + (size_t)b * CC * HH * WW;

    // In-flight split-stage state: 32 fp32 VGPRs (T14 lean split).
    float va[32];

    // Issue fp32 loads for x rows [rowT, rowT+9] x cols [x0-2, x0+31].
    auto stage_load = [&](int rowT) {
        if (!hasA) return;
        #pragma unroll
        for (int j = 0; j < 32; ++j) va[j] = 0.f;
        const int gy = rowT + yA, gx = x0 - 2 + xA;
        if (gy >= 0 && gy < HH && gx >= 0 && gx < WW) {
            const float* pa = xb + (gy * WW + gx);
            #pragma unroll
            for (int j = 0; j < 32; ++j) va[j] = pa[j * (HH * WW)];
        }
    };
    // Convert + write into xs (channels-last bf16).
    auto stage_write = [&]() {
        if (!hasA) return;
        #pragma unroll
        for (int k = 0; k < 8; ++k) {
            U2 w; w.x = cvtpk(va[4 * k + 0], va[4 * k + 1]);
                  w.y = cvtpk(va[4 * k + 2], va[4 * k + 3]);
            *(U2*)&xs[yA][xA][4 * k] = w;
        }
    };

    // conv1 iteration i: row gR = ybase-1+8i+wv, cols gC = x0-1+c (c=0..31).
    // Output -> hs[i&1][wv], zero-masked outside the image (conv2 SAME padding).
    auto conv1_iter = [&](int i) {
        f32x16 acc = {0,0,0,0,0,0,0,0,0,0,0,0,0,0,0,0};
        const unsigned short* xsb = &xs[wv][col][half * 8];
        #pragma unroll
        for (int st = 0; st < 18; ++st) {
            const int pos = st >> 1, s = st & 1;
            const int kh = pos / 3, kw = pos - kh * 3;
            const int off = (kh * 34 + kw) * CIP + s * 16;
            bf16x8 wf = __builtin_bit_cast(bf16x8, wq1[st * 64]);   // L2-hot, transient
            U4 xa;
            xa.lo = *(const U2*)(xsb + off);
            xa.hi = *(const U2*)(xsb + off + 4);
            acc = __builtin_amdgcn_mfma_f32_32x32x16_bf16(wf, __builtin_bit_cast(bf16x8, xa), acc, 0, 0, 0);
        }
        const int gR = ybase - 1 + 8 * i + wv;
        const int gC = x0 - 1 + col;
        const bool ok = ((unsigned)gR < (unsigned)HH) && ((unsigned)gC < (unsigned)WW);
        unsigned short* h = &hs[i & 1][wv][col][0];
        #pragma unroll
        for (int g = 0; g < 4; ++g) {
            int c0 = 8 * g + 4 * half;    // regs 4g..4g+3 -> consecutive co
            float a0 = fmaxf((acc[4 * g + 0] + bs1[c0 + 0]) * gs[c0 + 0], 0.f);
            float a1 = fmaxf((acc[4 * g + 1] + bs1[c0 + 1]) * gs[c0 + 1], 0.f);
            float a2 = fmaxf((acc[4 * g + 2] + bs1[c0 + 2]) * gs[c0 + 2], 0.f);
            float a3 = fmaxf((acc[4 * g + 3] + bs1[c0 + 3]) * gs[c0 + 3], 0.f);
            if (!ok) { a0 = 0.f; a1 = 0.f; a2 = 0.f; a3 = 0.f; }
            U2 w0; w0.x = cvtpk(a0, a1); w0.y = cvtpk(a2, a3);
            *(U2*)(h + c0) = w0;
        }
    };

    // conv2 iteration j: output row gO = ybase+8j+wv, cols gX = x0+n (n<30 valid).
    // Input row gO-1+kh lives in hs bank (j+(q>>3))&1, slot q&7, q = wv+kh.
    auto conv2_iter = [&](int j) {
        f32x16 acc = {0,0,0,0,0,0,0,0,0,0,0,0,0,0,0,0};
        const unsigned short* hb0 = &hs[j & 1][0][0][0];
        const unsigned short* hb1 = &hs[(j + 1) & 1][0][0][0];
        if (wv < 6) {
            // q = wv+kh <= 7: all in bank j&1, compile-time offsets.
            const unsigned short* p = hb0 + (wv * 34 + col) * CIP + half * 8;
            #pragma unroll
            for (int st = 0; st < 18; ++st) {
                const int pos = st >> 1, s = st & 1;
                const int kh = pos / 3, kw = pos - kh * 3;
                const int off = (kh * 34 + kw) * CIP + s * 16;
                bf16x8 wf = __builtin_bit_cast(bf16x8, wq2[st * 64]);
                U4 xa;
                xa.lo = *(const U2*)(p + off);
                xa.hi = *(const U2*)(p + off + 4);
                acc = __builtin_amdgcn_mfma_f32_32x32x16_bf16(wf, __builtin_bit_cast(bf16x8, xa), acc, 0, 0, 0);
            }
        } else {
            // wv = 6 or 7: q = wv+kh in {6..9}; bank select wave-uniform.
            #pragma unroll
            for (int st = 0; st < 18; ++st) {
                const int pos = st >> 1, s = st & 1;
                const int kh = pos / 3, kw = pos - kh * 3;
                const int q = wv + kh;
                const unsigned short* base = (q >= 8) ? hb1 : hb0;
                const unsigned short* p = base + (((q & 7) * 34) + col + kw) * CIP + s * 16 + half * 8;
                bf16x8 wf = __builtin_bit_cast(bf16x8, wq2[st * 64]);
                U4 xa;
                xa.lo = *(const U2*)(p);
                xa.hi = *(const U2*)(p + 4);
                acc = __builtin_amdgcn_mfma_f32_32x32x16_bf16(wf, __builtin_bit_cast(bf16x8, xa), acc, 0, 0, 0);
            }
        }
        const int gO = ybase + 8 * j + wv;
        const int gX = x0 + col;
        float* ob = out + (size_t)b * CC * HH * WW;
        const float* rb = x + (size_t)b * CC * HH * WW;
        if ((col < TWV) && (gX < WW)) {
            #pragma unroll
            for (int reg = 0; reg < 16; ++reg) {
                int co = (reg & 3) + 8 * (reg >> 2) + 4 * half;
                int idx = (co * HH + gO) * WW + gX;
                float v = (acc[reg] + bs2[co]) * gs[co];
                ob[idx] = fmaxf(v, 0.f) + rb[idx];
            }
        }
    };

    // ---- schedule: conv1 one iteration ahead of conv2; stage loads one ahead of writes ----
    stage_load(ybase - 2);
    stage_write();
    __syncthreads();                     // xs(0) ready (also fences gs/bs)
    stage_load(ybase - 2 + 8);           // loads for tile 1 fly under conv1(0)
    conv1_iter(0);
    #pragma unroll 1
    for (int i = 1; i <= NT; ++i) {
        __syncthreads();                 // B1: conv1(i-1) xs reads done; conv2(i-2) hs reads done
        stage_write();                   // xs <- tile i (loads long since returned)
        __syncthreads();                 // B2: xs(i) ready
        if (i < NT) stage_load(ybase - 2 + 8 * (i + 1));  // fly under conv1(i)+conv2(i-1)
        conv1_iter(i);                   // -> hs[i&1]
        __syncthreads();                 // B3: hs[i&1] visible
        conv2_iter(i - 1);               // reads hs[(i-1)&1] + hs[i&1] rows 0..1
    }
}

extern "C" void kernel_launch(void* const* d_in, const int* in_sizes, int n_in,
                              void* d_out, int out_size, void* d_ws, size_t ws_size,
                              hipStream_t stream) {
    const float* x  = (const float*)d_in[0];
    const float* gv = (const float*)d_in[1];
    const float* w1 = (const float*)d_in[2];
    const float* b1 = (const float*)d_in[3];
    const float* w2 = (const float*)d_in[4];
    const float* b2 = (const float*)d_in[5];
    float* out = (float*)d_out;

    unsigned short* wq = (unsigned short*)d_ws;   // 2 x 9216 bf16 frag tables

    wprep<<<36, 256, 0, stream>>>(w1, w2, wq);

    dim3 grid((WW + TWV - 1) / TWV, HH / (TH * NT), BB);  // (9, 8, 16) = 1152 blocks
    conv_fused<<<grid, 512, 0, stream>>>(x, wq, b1, b2, gv, out);
}